// Round 6
// baseline (277.905 us; speedup 1.0000x reference)
//
#include <hip/hip_runtime.h>
#include <math.h>

#define NN 50000
#define EE 600000
#define GG 250
#define HH 128

// prep_k grid split
#define B_CVT  6250
#define B_W    384
#define B_ROOT 196
#define B_ZD   196
#define B_ZH   125

typedef __attribute__((ext_vector_type(8))) short s16x8;
typedef __attribute__((ext_vector_type(8))) unsigned short u16x8;
typedef __attribute__((ext_vector_type(4))) unsigned short u16x4;
typedef __attribute__((ext_vector_type(4))) float f32x4;

__device__ __forceinline__ float b2f(unsigned short u) {
  union { unsigned int i; float f; } v; v.i = ((unsigned int)u) << 16; return v.f;
}
__device__ __forceinline__ unsigned short f2b(float f) {
  union { float f; unsigned int i; } v; v.f = f;
  unsigned int x = v.i;
  unsigned int r = (x + 0x7FFFu + ((x >> 16) & 1u)) >> 16;   // RNE, finite inputs
  return (unsigned short)r;
}

// ---------- fused prep: cvt_x | cvtW | root | zero-deg | zero-hg ----------
__global__ __launch_bounds__(256) void prep_k(
    const float* __restrict__ x, unsigned short* __restrict__ xb,
    const float* __restrict__ W0, const float* __restrict__ W1,
    const float* __restrict__ W2, const float* __restrict__ W3,
    const float* __restrict__ W4, const float* __restrict__ W5,
    unsigned short* __restrict__ WT,
    int* __restrict__ deg,
    const int* __restrict__ batch, int* __restrict__ root,
    float* __restrict__ hg) {
  int b = blockIdx.x, tid = threadIdx.x;
  if (b < B_CVT) {
    int i = b * 256 + tid;                       // x4 floats
    float4 v = *(const float4*)&x[i * 4];
    u16x4 o; o[0] = f2b(v.x); o[1] = f2b(v.y); o[2] = f2b(v.z); o[3] = f2b(v.w);
    *(u16x4*)&xb[i * 4] = o;
  } else if (b < B_CVT + B_W) {
    int bb = b - B_CVT;
    int w = bb >> 6;
    const float* W = (w == 0) ? W0 : (w == 1) ? W1 : (w == 2) ? W2
                     : (w == 3) ? W3 : (w == 4) ? W4 : W5;
    int idx = (bb & 63) * 256 + tid;
    int j = idx >> 7, k = idx & 127;
    WT[w * 16384 + j * 128 + k] = f2b(W[k * 128 + j]);   // WT[col][k]
  } else if (b < B_CVT + B_W + B_ROOT) {
    int n = (b - B_CVT - B_W) * 256 + tid;
    if (n < NN) {
      int bg = batch[n];
      if (n == 0 || batch[n - 1] != bg) root[bg] = n;
    }
  } else if (b < B_CVT + B_W + B_ROOT + B_ZD) {
    int n = (b - B_CVT - B_W - B_ROOT) * 256 + tid;
    if (n < NN) deg[n] = 0;
  } else {
    int i = (b - B_CVT - B_W - B_ROOT - B_ZD) * 256 + tid;   // < 32000
    hg[i] = 0.f;
  }
}

// ---------- histogram (after deg zeroed in prep) ----------
__global__ void hist_k(const int* __restrict__ dst, int* __restrict__ deg) {
  int e = blockIdx.x * 256 + threadIdx.x;
  if (e < EE) atomicAdd(&deg[dst[e]], 1);
}

// ---------- scan, phase 1 ----------
__global__ __launch_bounds__(1024) void scan1_k(const int* __restrict__ deg,
                                                int* __restrict__ excl,
                                                int* __restrict__ bsum) {
  __shared__ int sums[16];
  int tid = threadIdx.x;
  int i = blockIdx.x * 1024 + tid;
  int v = (i < NN) ? deg[i] : 0;
  int lane = tid & 63, wid = tid >> 6;
  int x = v;
  #pragma unroll
  for (int d = 1; d < 64; d <<= 1) { int y = __shfl_up(x, d); if (lane >= d) x += y; }
  if (lane == 63) sums[wid] = x;
  __syncthreads();
  if (wid == 0) {
    int s = (lane < 16) ? sums[lane] : 0;
    #pragma unroll
    for (int d = 1; d < 16; d <<= 1) { int y = __shfl_up(s, d); if (lane >= d) s += y; }
    if (lane < 16) sums[lane] = s;
  }
  __syncthreads();
  int ex = (wid ? sums[wid - 1] : 0) + x - v;
  if (i < NN) excl[i] = ex;
  if (tid == 1023) bsum[blockIdx.x] = sums[15];
}

// ---------- scan, phase 2+3 fused ----------
__global__ __launch_bounds__(256) void scanB_k(const int* __restrict__ excl,
                                               const int* __restrict__ bsum,
                                               int* __restrict__ rowptr,
                                               int* __restrict__ wp) {
  __shared__ int sboff[64];
  int tid = threadIdx.x;
  if (tid < 64) {
    int v = (tid < 49) ? bsum[tid] : 0;
    int x = v;
    #pragma unroll
    for (int d = 1; d < 64; d <<= 1) { int y = __shfl_up(x, d); if (tid >= d) x += y; }
    sboff[tid] = x - v;
  }
  __syncthreads();
  int i = blockIdx.x * 256 + tid;
  if (i < NN) {
    int r = excl[i] + sboff[i >> 10];
    rowptr[i] = r; wp[i] = r;
  }
  if (i == 0) rowptr[NN] = EE;
}

__global__ void scatter_k(const int* __restrict__ src, const int* __restrict__ dst,
                          int* __restrict__ wp, int* __restrict__ eidx) {
  int e = blockIdx.x * 256 + threadIdx.x;
  if (e < EE) {
    int p = atomicAdd(&wp[dst[e]], 1);
    eidx[p] = src[e];
  }
}

// ---------- mean aggregation: 16 lanes/node, 16 guarded row-loads in flight ----------
__global__ __launch_bounds__(256) void agg_k(const unsigned short* __restrict__ hb,
                                             const int* __restrict__ rowptr,
                                             const int* __restrict__ eidx,
                                             unsigned short* __restrict__ aggb) {
  int lane = threadIdx.x & 63, wid = threadIdx.x >> 6;
  int sub = lane >> 4, l16 = lane & 15;
  int base = sub * 16;                       // group's base lane in wave
  int node = blockIdx.x * 16 + wid * 4 + sub;
  int start = rowptr[node], end = rowptr[node + 1];
  float acc[8] = {0.f, 0.f, 0.f, 0.f, 0.f, 0.f, 0.f, 0.f};
  for (int c = start; c < end; c += 16) {
    int ecl = c + l16; if (ecl > end - 1) ecl = end - 1;
    int myidx = eidx[ecl];                   // 64B coalesced per group
    u16x8 rv[16];
    #pragma unroll
    for (int t = 0; t < 16; ++t) {
      int s = __shfl(myidx, base + t);
      u16x8 z = {0, 0, 0, 0, 0, 0, 0, 0};
      rv[t] = (c + t < end) ? *(const u16x8*)&hb[s * HH + l16 * 8] : z;
    }
    #pragma unroll
    for (int t = 0; t < 16; ++t) {
      #pragma unroll
      for (int j = 0; j < 8; ++j) acc[j] += b2f(rv[t][j]);
    }
  }
  int cnt = end - start;
  float inv = 1.f / (float)(cnt > 0 ? cnt : 1);
  u16x8 o;
  #pragma unroll
  for (int j = 0; j < 8; ++j) o[j] = f2b(acc[j] * inv);
  *(u16x8*)&aggb[node * HH + l16 * 8] = o;
}

// ---------- MFMA: (agg@Wl + bl + h@Wr) -> L2norm -> relu -> bf16 [+ fused max-pool] ----------
__global__ __launch_bounds__(256) void sage_k(
    const unsigned short* __restrict__ aggb, const unsigned short* __restrict__ hb,
    const unsigned short* __restrict__ WlT, const float* __restrict__ bl,
    const unsigned short* __restrict__ WrT, unsigned short* __restrict__ hout,
    float* __restrict__ hgmax) {
  int lane = threadIdx.x & 63, wid = threadIdx.x >> 6;
  int row0 = blockIdx.x * 64 + wid * 16;
  int l16 = lane & 15, hi = lane >> 4;
  int arow = row0 + l16; if (arow > NN - 1) arow = NN - 1;
  int aoff = arow * HH + hi * 8;
  int boff = l16 * HH + hi * 8;
  f32x4 acc[8];
  #pragma unroll
  for (int cc = 0; cc < 8; ++cc) acc[cc] = (f32x4){0.f, 0.f, 0.f, 0.f};
  #pragma unroll
  for (int kk = 0; kk < 4; ++kk) {
    s16x8 a = *(const s16x8*)&aggb[aoff + kk * 32];
    #pragma unroll
    for (int cc = 0; cc < 8; ++cc) {
      s16x8 b = *(const s16x8*)&WlT[boff + cc * 16 * HH + kk * 32];
      acc[cc] = __builtin_amdgcn_mfma_f32_16x16x32_bf16(a, b, acc[cc], 0, 0, 0);
    }
  }
  #pragma unroll
  for (int kk = 0; kk < 4; ++kk) {
    s16x8 a = *(const s16x8*)&hb[aoff + kk * 32];
    #pragma unroll
    for (int cc = 0; cc < 8; ++cc) {
      s16x8 b = *(const s16x8*)&WrT[boff + cc * 16 * HH + kk * 32];
      acc[cc] = __builtin_amdgcn_mfma_f32_16x16x32_bf16(a, b, acc[cc], 0, 0, 0);
    }
  }
  float v[8][4];
  float ss[4] = {0.f, 0.f, 0.f, 0.f};
  #pragma unroll
  for (int cc = 0; cc < 8; ++cc) {
    float bb = bl[cc * 16 + l16];
    #pragma unroll
    for (int i = 0; i < 4; ++i) {
      float t = acc[cc][i] + bb;
      v[cc][i] = t;
      ss[i] += t * t;
    }
  }
  #pragma unroll
  for (int m = 1; m < 16; m <<= 1) {
    #pragma unroll
    for (int i = 0; i < 4; ++i) ss[i] += __shfl_xor(ss[i], m);
  }
  float inv[4];
  #pragma unroll
  for (int i = 0; i < 4; ++i) inv[i] = 1.f / fmaxf(sqrtf(ss[i]), 1e-12f);
  #pragma unroll
  for (int cc = 0; cc < 8; ++cc) {
    #pragma unroll
    for (int i = 0; i < 4; ++i) {
      int row = row0 + hi * 4 + i;
      if (row < NN)
        hout[row * HH + cc * 16 + l16] = f2b(fmaxf(v[cc][i] * inv[i], 0.f));
    }
  }
  // fused global max pool (layer 3 only): thread's 4 rows share one graph (200%4==0)
  if (hgmax) {
    int r4 = row0 + hi * 4;
    if (r4 < NN) {
      int g = r4 / 200;
      #pragma unroll
      for (int cc = 0; cc < 8; ++cc) {
        float vm = 0.f;                       // relu floor
        #pragma unroll
        for (int i = 0; i < 4; ++i)
          if (r4 + i < NN) vm = fmaxf(vm, fmaxf(v[cc][i] * inv[i], 0.f));
        atomicMax((int*)&hgmax[g * HH + cc * 16 + l16], __float_as_int(vm));
      }
    }
  }
}

// ---------- final: news + lin2 + lin3 + sigmoid (hg from fused pool) ----------
__global__ __launch_bounds__(128) void final_k(
    const float* __restrict__ hg, const int* __restrict__ root,
    const float* __restrict__ x,
    const float* __restrict__ Wn, const float* __restrict__ bn,
    const float* __restrict__ W2, const float* __restrict__ b2,
    const float* __restrict__ W3, const float* __restrict__ b3,
    float* __restrict__ out) {
  __shared__ float hgr[128];
  __shared__ float xr[128];
  __shared__ float red[2];
  int g = blockIdx.x, j = threadIdx.x;
  int rt = root[g];
  hgr[j] = hg[g * HH + j];
  xr[j] = x[rt * HH + j];
  __syncthreads();
  float acc2 = b2[j];
  float accn = bn[j];
  for (int k = 0; k < 128; ++k) {
    acc2 += hgr[k] * W2[k * HH + j];
    accn += xr[k] * Wn[k * HH + j];
  }
  float c = fmaxf(acc2, 0.f) * W3[j] + fmaxf(accn, 0.f) * W3[HH + j];
  #pragma unroll
  for (int d = 1; d < 64; d <<= 1) c += __shfl_xor(c, d);
  if ((j & 63) == 0) red[j >> 6] = c;
  __syncthreads();
  if (j == 0) out[g] = 1.f / (1.f + expf(-(red[0] + red[1] + b3[0])));
}

extern "C" void kernel_launch(void* const* d_in, const int* in_sizes, int n_in,
                              void* d_out, int out_size, void* d_ws, size_t ws_size,
                              hipStream_t stream) {
  const float* x     = (const float*)d_in[0];
  const int*   adj   = (const int*)d_in[1];
  const int*   batch = (const int*)d_in[2];
  const float *W1l = (const float*)d_in[3],  *b1l = (const float*)d_in[4],  *W1r = (const float*)d_in[5];
  const float *W2l = (const float*)d_in[6],  *b2l = (const float*)d_in[7],  *W2r = (const float*)d_in[8];
  const float *W3l = (const float*)d_in[9],  *b3l = (const float*)d_in[10], *W3r = (const float*)d_in[11];
  const float *Wnews = (const float*)d_in[12], *bnews = (const float*)d_in[13];
  const float *Wlin2 = (const float*)d_in[14], *blin2 = (const float*)d_in[15];
  const float *Wlin3 = (const float*)d_in[16], *blin3 = (const float*)d_in[17];
  float* out = (float*)d_out;

  const int* srcp = adj;
  const int* dstp = adj + EE;

  char* ws = (char*)d_ws;
  size_t off = 0;
  auto alloc = [&](size_t bytes) -> void* {
    void* p = ws + off;
    off = (off + bytes + 255) & ~(size_t)255;
    return p;
  };
  int*   deg    = (int*)alloc(sizeof(int) * NN);
  int*   excl   = (int*)alloc(sizeof(int) * NN);
  int*   bsum   = (int*)alloc(sizeof(int) * 64);
  int*   rowptr = (int*)alloc(sizeof(int) * (NN + 1));
  int*   wp     = (int*)alloc(sizeof(int) * NN);
  int*   root   = (int*)alloc(sizeof(int) * GG);
  int*   eidx   = (int*)alloc(sizeof(int) * EE);
  unsigned short* WT   = (unsigned short*)alloc(sizeof(short) * 6 * 128 * 128);
  unsigned short* xb   = (unsigned short*)alloc(sizeof(short) * NN * HH);
  unsigned short* aggb = (unsigned short*)alloc(sizeof(short) * NN * HH);
  unsigned short* h1   = (unsigned short*)alloc(sizeof(short) * NN * HH);
  unsigned short* h2   = (unsigned short*)alloc(sizeof(short) * NN * HH);
  float* hg = (float*)alloc(sizeof(float) * GG * HH);
  (void)ws_size; (void)n_in; (void)in_sizes; (void)out_size;

  prep_k<<<B_CVT + B_W + B_ROOT + B_ZD + B_ZH, 256, 0, stream>>>(
      x, xb, W1l, W1r, W2l, W2r, W3l, W3r, WT, deg, batch, root, hg);
  hist_k<<<(EE + 255) / 256, 256, 0, stream>>>(dstp, deg);
  scan1_k<<<(NN + 1023) / 1024, 1024, 0, stream>>>(deg, excl, bsum);
  scanB_k<<<(NN + 255) / 256, 256, 0, stream>>>(excl, bsum, rowptr, wp);
  scatter_k<<<(EE + 255) / 256, 256, 0, stream>>>(srcp, dstp, wp, eidx);

  const int AGG_GRID = NN / 16;             // 3125
  const int GEMM_GRID = (NN + 63) / 64;     // 782
  const unsigned short* W1lT = WT + 0 * 16384;
  const unsigned short* W1rT = WT + 1 * 16384;
  const unsigned short* W2lT = WT + 2 * 16384;
  const unsigned short* W2rT = WT + 3 * 16384;
  const unsigned short* W3lT = WT + 4 * 16384;
  const unsigned short* W3rT = WT + 5 * 16384;

  agg_k<<<AGG_GRID, 256, 0, stream>>>(xb, rowptr, eidx, aggb);
  sage_k<<<GEMM_GRID, 256, 0, stream>>>(aggb, xb, W1lT, b1l, W1rT, h1, nullptr);
  agg_k<<<AGG_GRID, 256, 0, stream>>>(h1, rowptr, eidx, aggb);
  sage_k<<<GEMM_GRID, 256, 0, stream>>>(aggb, h1, W2lT, b2l, W2rT, h2, nullptr);
  agg_k<<<AGG_GRID, 256, 0, stream>>>(h2, rowptr, eidx, aggb);
  sage_k<<<GEMM_GRID, 256, 0, stream>>>(aggb, h2, W3lT, b3l, W3rT, h1, hg);

  final_k<<<GG, 128, 0, stream>>>(hg, root, x, Wnews, bnews,
                                  Wlin2, blin2, Wlin3, blin3, out);
}

// Round 7
// 219.393 us; speedup vs baseline: 1.2667x; 1.2667x over previous
//
#include <hip/hip_runtime.h>
#include <math.h>

#define NN 50000
#define EE 600000
#define GG 250
#define HH 128

// prep_k grid split
#define B_CVT  6250
#define B_W    384
#define B_ROOT 196
#define B_ZD   196
#define B_ZH   125

typedef __attribute__((ext_vector_type(8))) short s16x8;
typedef __attribute__((ext_vector_type(8))) unsigned short u16x8;
typedef __attribute__((ext_vector_type(4))) unsigned short u16x4;
typedef __attribute__((ext_vector_type(4))) float f32x4;

__device__ __forceinline__ float b2f(unsigned short u) {
  union { unsigned int i; float f; } v; v.i = ((unsigned int)u) << 16; return v.f;
}
__device__ __forceinline__ unsigned short f2b(float f) {
  union { float f; unsigned int i; } v; v.f = f;
  unsigned int x = v.i;
  unsigned int r = (x + 0x7FFFu + ((x >> 16) & 1u)) >> 16;   // RNE, finite inputs
  return (unsigned short)r;
}

// ---------- fused prep: cvt_x | cvtW | root | zero-deg | zero-hg ----------
__global__ __launch_bounds__(256) void prep_k(
    const float* __restrict__ x, unsigned short* __restrict__ xb,
    const float* __restrict__ W0, const float* __restrict__ W1,
    const float* __restrict__ W2, const float* __restrict__ W3,
    const float* __restrict__ W4, const float* __restrict__ W5,
    unsigned short* __restrict__ WT,
    int* __restrict__ deg,
    const int* __restrict__ batch, int* __restrict__ root,
    float* __restrict__ hg) {
  int b = blockIdx.x, tid = threadIdx.x;
  if (b < B_CVT) {
    int i = b * 256 + tid;                       // x4 floats
    float4 v = *(const float4*)&x[i * 4];
    u16x4 o; o[0] = f2b(v.x); o[1] = f2b(v.y); o[2] = f2b(v.z); o[3] = f2b(v.w);
    *(u16x4*)&xb[i * 4] = o;
  } else if (b < B_CVT + B_W) {
    int bb = b - B_CVT;
    int w = bb >> 6;
    const float* W = (w == 0) ? W0 : (w == 1) ? W1 : (w == 2) ? W2
                     : (w == 3) ? W3 : (w == 4) ? W4 : W5;
    int idx = (bb & 63) * 256 + tid;
    int j = idx >> 7, k = idx & 127;
    WT[w * 16384 + j * 128 + k] = f2b(W[k * 128 + j]);   // WT[col][k]
  } else if (b < B_CVT + B_W + B_ROOT) {
    int n = (b - B_CVT - B_W) * 256 + tid;
    if (n < NN) {
      int bg = batch[n];
      if (n == 0 || batch[n - 1] != bg) root[bg] = n;
    }
  } else if (b < B_CVT + B_W + B_ROOT + B_ZD) {
    int n = (b - B_CVT - B_W - B_ROOT) * 256 + tid;
    if (n < NN) deg[n] = 0;
  } else {
    int i = (b - B_CVT - B_W - B_ROOT - B_ZD) * 256 + tid;   // < 32000
    hg[i] = 0.f;
  }
}

// ---------- histogram (after deg zeroed in prep) ----------
__global__ void hist_k(const int* __restrict__ dst, int* __restrict__ deg) {
  int e = blockIdx.x * 256 + threadIdx.x;
  if (e < EE) atomicAdd(&deg[dst[e]], 1);
}

// ---------- scan, phase 1 ----------
__global__ __launch_bounds__(1024) void scan1_k(const int* __restrict__ deg,
                                                int* __restrict__ excl,
                                                int* __restrict__ bsum) {
  __shared__ int sums[16];
  int tid = threadIdx.x;
  int i = blockIdx.x * 1024 + tid;
  int v = (i < NN) ? deg[i] : 0;
  int lane = tid & 63, wid = tid >> 6;
  int x = v;
  #pragma unroll
  for (int d = 1; d < 64; d <<= 1) { int y = __shfl_up(x, d); if (lane >= d) x += y; }
  if (lane == 63) sums[wid] = x;
  __syncthreads();
  if (wid == 0) {
    int s = (lane < 16) ? sums[lane] : 0;
    #pragma unroll
    for (int d = 1; d < 16; d <<= 1) { int y = __shfl_up(s, d); if (lane >= d) s += y; }
    if (lane < 16) sums[lane] = s;
  }
  __syncthreads();
  int ex = (wid ? sums[wid - 1] : 0) + x - v;
  if (i < NN) excl[i] = ex;
  if (tid == 1023) bsum[blockIdx.x] = sums[15];
}

// ---------- scan, phase 2+3 fused ----------
__global__ __launch_bounds__(256) void scanB_k(const int* __restrict__ excl,
                                               const int* __restrict__ bsum,
                                               int* __restrict__ rowptr,
                                               int* __restrict__ wp) {
  __shared__ int sboff[64];
  int tid = threadIdx.x;
  if (tid < 64) {
    int v = (tid < 49) ? bsum[tid] : 0;
    int x = v;
    #pragma unroll
    for (int d = 1; d < 64; d <<= 1) { int y = __shfl_up(x, d); if (tid >= d) x += y; }
    sboff[tid] = x - v;
  }
  __syncthreads();
  int i = blockIdx.x * 256 + tid;
  if (i < NN) {
    int r = excl[i] + sboff[i >> 10];
    rowptr[i] = r; wp[i] = r;
  }
  if (i == 0) rowptr[NN] = EE;
}

__global__ void scatter_k(const int* __restrict__ src, const int* __restrict__ dst,
                          int* __restrict__ wp, int* __restrict__ eidx) {
  int e = blockIdx.x * 256 + threadIdx.x;
  if (e < EE) {
    int p = atomicAdd(&wp[dst[e]], 1);
    eidx[p] = src[e];
  }
}

// ---------- mean aggregation: 16 lanes/node, 16 guarded row-loads in flight ----------
__global__ __launch_bounds__(256) void agg_k(const unsigned short* __restrict__ hb,
                                             const int* __restrict__ rowptr,
                                             const int* __restrict__ eidx,
                                             unsigned short* __restrict__ aggb) {
  int lane = threadIdx.x & 63, wid = threadIdx.x >> 6;
  int sub = lane >> 4, l16 = lane & 15;
  int base = sub * 16;                       // group's base lane in wave
  int node = blockIdx.x * 16 + wid * 4 + sub;
  int start = rowptr[node], end = rowptr[node + 1];
  float acc[8] = {0.f, 0.f, 0.f, 0.f, 0.f, 0.f, 0.f, 0.f};
  for (int c = start; c < end; c += 16) {
    int ecl = c + l16; if (ecl > end - 1) ecl = end - 1;
    int myidx = eidx[ecl];                   // 64B coalesced per group
    u16x8 rv[16];
    #pragma unroll
    for (int t = 0; t < 16; ++t) {
      int s = __shfl(myidx, base + t);
      u16x8 z = {0, 0, 0, 0, 0, 0, 0, 0};
      rv[t] = (c + t < end) ? *(const u16x8*)&hb[s * HH + l16 * 8] : z;
    }
    #pragma unroll
    for (int t = 0; t < 16; ++t) {
      #pragma unroll
      for (int j = 0; j < 8; ++j) acc[j] += b2f(rv[t][j]);
    }
  }
  int cnt = end - start;
  float inv = 1.f / (float)(cnt > 0 ? cnt : 1);
  u16x8 o;
  #pragma unroll
  for (int j = 0; j < 8; ++j) o[j] = f2b(acc[j] * inv);
  *(u16x8*)&aggb[node * HH + l16 * 8] = o;
}

// ---------- MFMA sage layer, LDS-staged weights ----------
// WlT points at 64KB of [Wl^T ; Wr^T] (contiguous). Block = 128 rows, 4 waves,
// each wave 2 row-tiles of 16 so every B-fragment ds_read feeds 2 MFMAs.
__global__ __launch_bounds__(256) void sage_k(
    const unsigned short* __restrict__ aggb, const unsigned short* __restrict__ hb,
    const unsigned short* __restrict__ WlT, const float* __restrict__ bl,
    unsigned short* __restrict__ hout, float* __restrict__ hgmax) {
  __shared__ unsigned short sW[32768];   // 64 KB: [0..16383]=Wl^T, [16384..]=Wr^T
  int tid = threadIdx.x;

  // stage both weight matrices, 16B-unit XOR swizzle (unit ^ row&7) -> 2-way banks
  #pragma unroll
  for (int i = 0; i < 16; ++i) {
    int u = i * 256 + tid;
    int row = u >> 4, unit = u & 15;
    u16x8 w = *(const u16x8*)&WlT[row * 128 + unit * 8];
    *(u16x8*)&sW[row * 128 + ((unit ^ (row & 7)) * 8)] = w;
  }
  __syncthreads();

  int lane = tid & 63, wid = tid >> 6;
  int l16 = lane & 15, hi = lane >> 4;
  int rbase = blockIdx.x * 128 + wid * 32;

  // A fragments for 2 row-tiles, both inputs, staged in registers
  s16x8 aA[2][4], aH[2][4];
  #pragma unroll
  for (int rt = 0; rt < 2; ++rt) {
    int ar = rbase + rt * 16 + l16; if (ar > NN - 1) ar = NN - 1;
    #pragma unroll
    for (int kk = 0; kk < 4; ++kk) {
      aA[rt][kk] = *(const s16x8*)&aggb[ar * HH + kk * 32 + hi * 8];
      aH[rt][kk] = *(const s16x8*)&hb[ar * HH + kk * 32 + hi * 8];
    }
  }

  f32x4 acc[2][8];
  #pragma unroll
  for (int rt = 0; rt < 2; ++rt)
    #pragma unroll
    for (int cc = 0; cc < 8; ++cc) acc[rt][cc] = (f32x4){0.f, 0.f, 0.f, 0.f};

  #pragma unroll
  for (int cc = 0; cc < 8; ++cc) {
    int brow = cc * 16 + l16;
    int bb = brow * 128;
    int sw = brow & 7;
    #pragma unroll
    for (int kk = 0; kk < 4; ++kk) {
      int un = (kk * 4 + hi) ^ sw;
      s16x8 bL = *(const s16x8*)&sW[bb + un * 8];
      acc[0][cc] = __builtin_amdgcn_mfma_f32_16x16x32_bf16(aA[0][kk], bL, acc[0][cc], 0, 0, 0);
      acc[1][cc] = __builtin_amdgcn_mfma_f32_16x16x32_bf16(aA[1][kk], bL, acc[1][cc], 0, 0, 0);
      s16x8 bR = *(const s16x8*)&sW[16384 + bb + un * 8];
      acc[0][cc] = __builtin_amdgcn_mfma_f32_16x16x32_bf16(aH[0][kk], bR, acc[0][cc], 0, 0, 0);
      acc[1][cc] = __builtin_amdgcn_mfma_f32_16x16x32_bf16(aH[1][kk], bR, acc[1][cc], 0, 0, 0);
    }
  }

  // epilogue per row-tile: bias, L2 norm, relu, store (+ fused max-pool layer 3)
  #pragma unroll
  for (int rt = 0; rt < 2; ++rt) {
    int rtb = rbase + rt * 16;
    float v[8][4];
    float ss[4] = {0.f, 0.f, 0.f, 0.f};
    #pragma unroll
    for (int cc = 0; cc < 8; ++cc) {
      float bb = bl[cc * 16 + l16];
      #pragma unroll
      for (int i = 0; i < 4; ++i) {
        float t = acc[rt][cc][i] + bb;
        v[cc][i] = t;
        ss[i] += t * t;
      }
    }
    #pragma unroll
    for (int m = 1; m < 16; m <<= 1) {
      #pragma unroll
      for (int i = 0; i < 4; ++i) ss[i] += __shfl_xor(ss[i], m);
    }
    float inv[4];
    #pragma unroll
    for (int i = 0; i < 4; ++i) inv[i] = 1.f / fmaxf(sqrtf(ss[i]), 1e-12f);
    #pragma unroll
    for (int cc = 0; cc < 8; ++cc) {
      #pragma unroll
      for (int i = 0; i < 4; ++i) {
        int row = rtb + hi * 4 + i;
        if (row < NN)
          hout[row * HH + cc * 16 + l16] = f2b(fmaxf(v[cc][i] * inv[i], 0.f));
      }
    }
    if (hgmax) {
      int r4 = rtb + hi * 4;
      if (r4 < NN) {
        int g = r4 / 200;                    // 4-row strips never cross graphs
        #pragma unroll
        for (int cc = 0; cc < 8; ++cc) {
          float vm = 0.f;                    // relu floor
          #pragma unroll
          for (int i = 0; i < 4; ++i)
            if (r4 + i < NN) vm = fmaxf(vm, fmaxf(v[cc][i] * inv[i], 0.f));
          atomicMax((int*)&hgmax[g * HH + cc * 16 + l16], __float_as_int(vm));
        }
      }
    }
  }
}

// ---------- final: news + lin2 + lin3 + sigmoid (hg from fused pool) ----------
__global__ __launch_bounds__(128) void final_k(
    const float* __restrict__ hg, const int* __restrict__ root,
    const float* __restrict__ x,
    const float* __restrict__ Wn, const float* __restrict__ bn,
    const float* __restrict__ W2, const float* __restrict__ b2,
    const float* __restrict__ W3, const float* __restrict__ b3,
    float* __restrict__ out) {
  __shared__ float hgr[128];
  __shared__ float xr[128];
  __shared__ float red[2];
  int g = blockIdx.x, j = threadIdx.x;
  int rt = root[g];
  hgr[j] = hg[g * HH + j];
  xr[j] = x[rt * HH + j];
  __syncthreads();
  float acc2 = b2[j];
  float accn = bn[j];
  for (int k = 0; k < 128; ++k) {
    acc2 += hgr[k] * W2[k * HH + j];
    accn += xr[k] * Wn[k * HH + j];
  }
  float c = fmaxf(acc2, 0.f) * W3[j] + fmaxf(accn, 0.f) * W3[HH + j];
  #pragma unroll
  for (int d = 1; d < 64; d <<= 1) c += __shfl_xor(c, d);
  if ((j & 63) == 0) red[j >> 6] = c;
  __syncthreads();
  if (j == 0) out[g] = 1.f / (1.f + expf(-(red[0] + red[1] + b3[0])));
}

extern "C" void kernel_launch(void* const* d_in, const int* in_sizes, int n_in,
                              void* d_out, int out_size, void* d_ws, size_t ws_size,
                              hipStream_t stream) {
  const float* x     = (const float*)d_in[0];
  const int*   adj   = (const int*)d_in[1];
  const int*   batch = (const int*)d_in[2];
  const float *W1l = (const float*)d_in[3],  *b1l = (const float*)d_in[4],  *W1r = (const float*)d_in[5];
  const float *W2l = (const float*)d_in[6],  *b2l = (const float*)d_in[7],  *W2r = (const float*)d_in[8];
  const float *W3l = (const float*)d_in[9],  *b3l = (const float*)d_in[10], *W3r = (const float*)d_in[11];
  const float *Wnews = (const float*)d_in[12], *bnews = (const float*)d_in[13];
  const float *Wlin2 = (const float*)d_in[14], *blin2 = (const float*)d_in[15];
  const float *Wlin3 = (const float*)d_in[16], *blin3 = (const float*)d_in[17];
  float* out = (float*)d_out;

  const int* srcp = adj;
  const int* dstp = adj + EE;

  char* ws = (char*)d_ws;
  size_t off = 0;
  auto alloc = [&](size_t bytes) -> void* {
    void* p = ws + off;
    off = (off + bytes + 255) & ~(size_t)255;
    return p;
  };
  int*   deg    = (int*)alloc(sizeof(int) * NN);
  int*   excl   = (int*)alloc(sizeof(int) * NN);
  int*   bsum   = (int*)alloc(sizeof(int) * 64);
  int*   rowptr = (int*)alloc(sizeof(int) * (NN + 1));
  int*   wp     = (int*)alloc(sizeof(int) * NN);
  int*   root   = (int*)alloc(sizeof(int) * GG);
  int*   eidx   = (int*)alloc(sizeof(int) * EE);
  unsigned short* WT   = (unsigned short*)alloc(sizeof(short) * 6 * 128 * 128);
  unsigned short* xb   = (unsigned short*)alloc(sizeof(short) * NN * HH);
  unsigned short* aggb = (unsigned short*)alloc(sizeof(short) * NN * HH);
  unsigned short* h1   = (unsigned short*)alloc(sizeof(short) * NN * HH);
  unsigned short* h2   = (unsigned short*)alloc(sizeof(short) * NN * HH);
  float* hg = (float*)alloc(sizeof(float) * GG * HH);
  (void)ws_size; (void)n_in; (void)in_sizes; (void)out_size;

  prep_k<<<B_CVT + B_W + B_ROOT + B_ZD + B_ZH, 256, 0, stream>>>(
      x, xb, W1l, W1r, W2l, W2r, W3l, W3r, WT, deg, batch, root, hg);
  hist_k<<<(EE + 255) / 256, 256, 0, stream>>>(dstp, deg);
  scan1_k<<<(NN + 1023) / 1024, 1024, 0, stream>>>(deg, excl, bsum);
  scanB_k<<<(NN + 255) / 256, 256, 0, stream>>>(excl, bsum, rowptr, wp);
  scatter_k<<<(EE + 255) / 256, 256, 0, stream>>>(srcp, dstp, wp, eidx);

  const int AGG_GRID = NN / 16;              // 3125
  const int GEMM_GRID = (NN + 127) / 128;    // 391

  agg_k<<<AGG_GRID, 256, 0, stream>>>(xb, rowptr, eidx, aggb);
  sage_k<<<GEMM_GRID, 256, 0, stream>>>(aggb, xb, WT + 0 * 16384, b1l, h1, nullptr);
  agg_k<<<AGG_GRID, 256, 0, stream>>>(h1, rowptr, eidx, aggb);
  sage_k<<<GEMM_GRID, 256, 0, stream>>>(aggb, h1, WT + 2 * 16384, b2l, h2, nullptr);
  agg_k<<<AGG_GRID, 256, 0, stream>>>(h2, rowptr, eidx, aggb);
  sage_k<<<GEMM_GRID, 256, 0, stream>>>(aggb, h2, WT + 4 * 16384, b3l, h1, hg);

  final_k<<<GG, 128, 0, stream>>>(hg, root, x, Wnews, bnews,
                                  Wlin2, blin2, Wlin3, blin3, out);
}